// Round 14
// baseline (96.331 us; speedup 1.0000x reference)
//
#include <hip/hip_runtime.h>

#define POS_IN 63
#define HID 128
#define TOTAL 8789
#define NB 32
#define NPTS 65536

#define PB_OFF 8064
#define SW_OFF 8192
#define SB_OFF 8320
#define CW_OFF 8321
#define CB_OFF 8786

#define BLOCKS_PER_BATCH 16
#define PTS_PER_BLOCK (NPTS / BLOCKS_PER_BATCH) /* 4096 */
#define ITERS (PTS_PER_BLOCK / 256)             /* 16 */

typedef __attribute__((ext_vector_type(8))) short s16x8;
typedef __attribute__((ext_vector_type(4))) float f32x4;
typedef __attribute__((ext_vector_type(2))) float f32x2;
typedef __bf16 bf16x2 __attribute__((ext_vector_type(2)));

// f32 -> bf16 RNE, integer path (setup only; proven R2)
__device__ __forceinline__ unsigned short f2bf(float v) {
    unsigned u = __builtin_bit_cast(unsigned, v);
    unsigned r = 0x7fffu + ((u >> 16) & 1u);
    return (unsigned short)((u + r) >> 16);
}
// hot-path pack: native __bf16 casts -> v_cvt_pk_bf16_f32 (proven R6-R13)
__device__ __forceinline__ unsigned pk2(float a, float b) {
    bf16x2 v;
    v[0] = (__bf16)a;
    v[1] = (__bf16)b;
    return __builtin_bit_cast(unsigned, v);
}

// positional encoding -> 8 packed uint4 (trig packed; proven R13)
__device__ __forceinline__ void enc_pos(float x, float y, float z, uint4* q) {
    float e[64];
    e[0] = x; e[1] = y; e[2] = z; e[63] = 1.0f;   // 1.0 hits bias row of wB
    f32x2 s2, c2;
    s2[0] = __sinf(x); s2[1] = __sinf(y);
    c2[0] = __cosf(x); c2[1] = __cosf(y);
    float sz = __sinf(z), cz = __cosf(z);
    e[3] = s2[0]; e[13] = s2[1]; e[23] = sz;
    e[33] = c2[0]; e[43] = c2[1]; e[53] = cz;
    #pragma unroll
    for (int f = 1; f < 10; ++f) {
        f32x2 ns = 2.f * s2 * c2;
        f32x2 nc = 1.f - 2.f * s2 * s2;
        s2 = ns; c2 = nc;
        float nsz = 2.f * sz * cz;
        float ncz = 1.f - 2.f * sz * sz;
        sz = nsz; cz = ncz;
        e[3 + f] = s2[0]; e[13 + f] = s2[1]; e[23 + f] = sz;
        e[33 + f] = c2[0]; e[43 + f] = c2[1]; e[53 + f] = cz;
    }
    #pragma unroll
    for (int kq = 0; kq < 8; ++kq) {
        q[kq].x = pk2(e[kq * 8 + 0], e[kq * 8 + 1]);
        q[kq].y = pk2(e[kq * 8 + 2], e[kq * 8 + 3]);
        q[kq].z = pk2(e[kq * 8 + 4], e[kq * 8 + 5]);
        q[kq].w = pk2(e[kq * 8 + 6], e[kq * 8 + 7]);
    }
}
// dir encoding -> 4 packed uint4 (slot 27 = 1.0 for bias; proven R13)
__device__ __forceinline__ void enc_dir(float dx, float dy, float dz, uint4* qd) {
    float d[32];
    d[0] = dx; d[1] = dy; d[2] = dz;
    d[27] = 1.0f; d[28] = 0.f; d[29] = 0.f; d[30] = 0.f; d[31] = 0.f;
    f32x2 s2, c2;
    s2[0] = __sinf(dx); s2[1] = __sinf(dy);
    c2[0] = __cosf(dx); c2[1] = __cosf(dy);
    float sz = __sinf(dz), cz = __cosf(dz);
    d[3] = s2[0]; d[7] = s2[1]; d[11] = sz;
    d[15] = c2[0]; d[19] = c2[1]; d[23] = cz;
    #pragma unroll
    for (int f = 1; f < 4; ++f) {
        f32x2 ns = 2.f * s2 * c2;
        f32x2 nc = 1.f - 2.f * s2 * s2;
        s2 = ns; c2 = nc;
        float nsz = 2.f * sz * cz;
        float ncz = 1.f - 2.f * sz * sz;
        sz = nsz; cz = ncz;
        d[3 + f] = s2[0]; d[7 + f] = s2[1]; d[11 + f] = sz;
        d[15 + f] = c2[0]; d[19 + f] = c2[1]; d[23 + f] = cz;
    }
    #pragma unroll
    for (int kq = 0; kq < 4; ++kq) {
        qd[kq].x = pk2(d[kq * 8 + 0], d[kq * 8 + 1]);
        qd[kq].y = pk2(d[kq * 8 + 2], d[kq * 8 + 3]);
        qd[kq].z = pk2(d[kq * 8 + 4], d[kq * 8 + 5]);
        qd[kq].w = pk2(d[kq * 8 + 6], d[kq * 8 + 7]);
    }
}

// __launch_bounds__(256) only — (256,4) mis-executes (R3/R4).
// R14: chunk-level software pipeline — next chunk's encoding (serial VALU)
// overlaps current chunk's MFMA/DS tile phase. Branchless body (clamped
// last-iter coords) keeps one BB so the scheduler can interleave.
__global__ __launch_bounds__(256) void nerf_mlp_kernel(
        const float* __restrict__ params,
        const float* __restrict__ points,
        const float* __restrict__ dirs,
        float* __restrict__ out)
{
    // LDS: [0,32768) per-wave enc bufs (8KB), aliased at start by pw stage
    // ([128][72] ushort = 18432B). [32768,49152) per-wave dir bufs (4KB).
    __shared__ __align__(16) unsigned char smem[49152];
    unsigned short* stage = (unsigned short*)smem;

    const int tid = threadIdx.x;
    const int lane = tid & 63;
    const int wid = tid >> 6;
    const int b = blockIdx.y;
    const float* P = params + (size_t)b * TOTAL;

    // ---- stage pw (128x63) as bf16, row stride 72; k=63 column = layer-1
    // bias (bias-in-K: e[63]=1.0). Proven R6-R13.
    for (int idx = tid; idx < 8064; idx += 256) {
        int n = idx / 63;
        int k = idx - n * 63;
        stage[n * 72 + k] = f2bf(P[idx]);
        if (k == 0) stage[n * 72 + 63] = f2bf(P[PB_OFF + n]);
    }
    __syncthreads();

    const int c = lane & 15;   // tile col: point-in-tile (and o for layer-2)
    const int kg = lane >> 4;  // k-group 0..3

    // ---- 16 persistent layer-1 fragments: lane holds pw[n=nt*16+c][k slice]
    s16x8 wB[8][2];
    #pragma unroll
    for (int nt = 0; nt < 8; ++nt) {
        #pragma unroll
        for (int kh = 0; kh < 2; ++kh) {
            int n = nt * 16 + c;
            int k = kh * 32 + kg * 8;
            uint4 raw = *(const uint4*)&stage[n * 72 + k];
            wB[nt][kh] = __builtin_bit_cast(s16x8, raw);
        }
    }

    // ---- layer-2 h-chunk B frags, PERMUTED to match A2's local packing
    // (proven R10-R13): slot (kg,e) = logical h (e<4?2m:2m+1)*16+kg*4+(e&3).
    s16x8 wB2h[4];
    #pragma unroll
    for (int m = 0; m < 4; ++m) {
        uint4 dd = make_uint4(0u, 0u, 0u, 0u);
        if (c < 4) {
            const int base = (c == 3) ? SW_OFF : (CW_OFF + c * 155);
            const int b0 = base + 32 * m + kg * 4;
            dd.x = pk2(P[b0 + 0],  P[b0 + 1]);
            dd.y = pk2(P[b0 + 2],  P[b0 + 3]);
            dd.z = pk2(P[b0 + 16], P[b0 + 17]);
            dd.w = pk2(P[b0 + 18], P[b0 + 19]);
        }
        wB2h[m] = __builtin_bit_cast(s16x8, dd);
    }
    // ---- dir+bias chunk B frag: k_loc = kg*8+e; <27 -> dir weights,
    // ==27 -> bias (proven R10-R13)
    s16x8 wB2d;
    {
        float vals[8];
        #pragma unroll
        for (int e = 0; e < 8; ++e) {
            int k_loc = kg * 8 + e;
            float v = 0.f;
            if (c < 3) {
                if (k_loc < 27)       v = P[CW_OFF + c * 155 + 128 + k_loc];
                else if (k_loc == 27) v = P[CB_OFF + c];
            } else if (c == 3) {
                if (k_loc == 27)      v = P[SB_OFF];
            }
            vals[e] = v;
        }
        uint4 dd;
        dd.x = pk2(vals[0], vals[1]);
        dd.y = pk2(vals[2], vals[3]);
        dd.z = pk2(vals[4], vals[5]);
        dd.w = pk2(vals[6], vals[7]);
        wB2d = __builtin_bit_cast(s16x8, dd);
    }
    __syncthreads();   // stage area -> enc buffers

    unsigned char* encb = smem + wid * 8192;            // [kq][pt][16B]
    unsigned char* dirb = smem + 32768 + wid * 4096;    // [kq2][pt][16B]

    const size_t bpts = (size_t)b * NPTS;
    const int n0b = blockIdx.x * PTS_PER_BLOCK;

    // ---- prologue: encode chunk 0 into registers
    uint4 q[8], qd[4];
    {
        const int p0 = n0b + wid * 64 + lane;
        const float* pp = points + (bpts + p0) * 3;
        const float* dd = dirs + (bpts + p0) * 3;
        enc_pos(pp[0], pp[1], pp[2], q);
        enc_dir(dd[0], dd[1], dd[2], qd);
    }

    #pragma unroll 2
    for (int it = 0; it < ITERS; ++it) {
        const int n0 = n0b + it * 256 + wid * 64;  // this wave's 64-pt chunk

        // ---- 1. write current chunk's enc to LDS (WAR vs prev iter's
        // reads is safe: same-wave DS ops execute in order, proven R7-R13)
        #pragma unroll
        for (int kq = 0; kq < 8; ++kq)
            *(uint4*)(encb + kq * 1024 + lane * 16) = q[kq];
        #pragma unroll
        for (int kq = 0; kq < 4; ++kq)
            *(uint4*)(dirb + kq * 1024 + lane * 16) = qd[kq];

        // ---- 2. next chunk coords (clamped on last iter: branchless body
        // keeps one BB so enc(i+1) interleaves with tiles(i))
        const int itn = (it + 1 < ITERS) ? (it + 1) : it;
        const int pn = n0b + itn * 256 + wid * 64 + lane;
        const float* ppn = points + (bpts + pn) * 3;
        const float* ddn = dirs + (bpts + pn) * 3;
        float nx = ppn[0], ny = ppn[1], nz = ppn[2];
        float ndx = ddn[0], ndy = ddn[1], ndz = ddn[2];

        // ---- 3. encode next chunk into fresh regs (pure VALU/trans —
        // co-issues with the MFMA/DS tile phase below)
        uint4 qn[8], qdn[4];
        enc_pos(nx, ny, nz, qn);
        enc_dir(ndx, ndy, ndz, qdn);

        float* outp = out + (bpts + n0) * 4;

        // ---- 4. tiles for current chunk (reads this iter's LDS writes)
        #pragma unroll
        for (int t = 0; t < 4; ++t) {
            uint4 a0r = *(const uint4*)(encb + kg * 1024 + (t * 16 + c) * 16);
            uint4 a1r = *(const uint4*)(encb + (4 + kg) * 1024 + (t * 16 + c) * 16);
            s16x8 A0 = __builtin_bit_cast(s16x8, a0r);
            s16x8 A1 = __builtin_bit_cast(s16x8, a1r);

            uint4 adr = *(const uint4*)(dirb + kg * 1024 + (t * 16 + c) * 16);
            s16x8 A2d = __builtin_bit_cast(s16x8, adr);
            f32x4 acc2a = (f32x4){0.f, 0.f, 0.f, 0.f};
            f32x4 acc2b = (f32x4){0.f, 0.f, 0.f, 0.f};
            acc2a = __builtin_amdgcn_mfma_f32_16x16x32_bf16(A2d, wB2d, acc2a, 0, 0, 0);

            // layer-1 (swapped: D[h][pt], pt = t*16+c) fused with layer-2
            // via permuted-B; two parallel acc2 chains (proven R10-R13)
            #pragma unroll
            for (int m = 0; m < 4; ++m) {
                f32x4 accA = (f32x4){0.f, 0.f, 0.f, 0.f};
                f32x4 accB = (f32x4){0.f, 0.f, 0.f, 0.f};
                accA = __builtin_amdgcn_mfma_f32_16x16x32_bf16(wB[2 * m][0], A0, accA, 0, 0, 0);
                accA = __builtin_amdgcn_mfma_f32_16x16x32_bf16(wB[2 * m][1], A1, accA, 0, 0, 0);
                accB = __builtin_amdgcn_mfma_f32_16x16x32_bf16(wB[2 * m + 1][0], A0, accB, 0, 0, 0);
                accB = __builtin_amdgcn_mfma_f32_16x16x32_bf16(wB[2 * m + 1][1], A1, accB, 0, 0, 0);
                uint4 dd2;
                dd2.x = pk2(fmaxf(accA[0], 0.f), fmaxf(accA[1], 0.f));
                dd2.y = pk2(fmaxf(accA[2], 0.f), fmaxf(accA[3], 0.f));
                dd2.z = pk2(fmaxf(accB[0], 0.f), fmaxf(accB[1], 0.f));
                dd2.w = pk2(fmaxf(accB[2], 0.f), fmaxf(accB[3], 0.f));
                s16x8 A2 = __builtin_bit_cast(s16x8, dd2);
                if (m & 1)
                    acc2b = __builtin_amdgcn_mfma_f32_16x16x32_bf16(A2, wB2h[m], acc2b, 0, 0, 0);
                else
                    acc2a = __builtin_amdgcn_mfma_f32_16x16x32_bf16(A2, wB2h[m], acc2a, 0, 0, 0);
            }

            // D2: lane (c,kg) reg j = (pt = t*16+kg*4+j, o = c), valid c<4.
            if (c < 4) {
                #pragma unroll
                for (int j = 0; j < 4; ++j) {
                    float v = acc2a[j] + acc2b[j];
                    float sig = 1.f / (1.f + __expf(-v));
                    v = (c < 3) ? sig : v;      // sigmoid on color only
                    outp[t * 64 + kg * 16 + j * 4 + c] = v;
                }
            }
        }

        // ---- 5. rotate pipeline regs (unroll-2 renames these away)
        #pragma unroll
        for (int k = 0; k < 8; ++k) q[k] = qn[k];
        #pragma unroll
        for (int k = 0; k < 4; ++k) qd[k] = qdn[k];
    }
}

extern "C" void kernel_launch(void* const* d_in, const int* in_sizes, int n_in,
                              void* d_out, int out_size, void* d_ws, size_t ws_size,
                              hipStream_t stream) {
    const float* params = (const float*)d_in[0];
    const float* points = (const float*)d_in[1];
    const float* dirs   = (const float*)d_in[2];
    float* out = (float*)d_out;
    dim3 grid(BLOCKS_PER_BATCH, NB);
    nerf_mlp_kernel<<<grid, 256, 0, stream>>>(params, points, dirs, out);
}